// Round 15
// baseline (627.288 us; speedup 1.0000x reference)
//
#include <hip/hip_runtime.h>

#define EMBED 32
#define HIDDEN 64
#define NCLS 10

// ============ CSR construction (round-6 proven) ============

__global__ void deg_kernel(const int* __restrict__ dst, int* __restrict__ deg, int nEdges) {
    int e = blockIdx.x * blockDim.x + threadIdx.x;
    if (e >= nEdges) return;
    atomicAdd(&deg[dst[e]], 1);
}

__global__ void block_sum_kernel(const int* __restrict__ deg, int* __restrict__ blockSums, int n) {
    __shared__ int s[256];
    int i = blockIdx.x * 256 + threadIdx.x;
    s[threadIdx.x] = (i < n) ? deg[i] : 0;
    __syncthreads();
    for (int off = 128; off > 0; off >>= 1) {
        if (threadIdx.x < off) s[threadIdx.x] += s[threadIdx.x + off];
        __syncthreads();
    }
    if (threadIdx.x == 0) blockSums[blockIdx.x] = s[0];
}

__global__ void scan_sums_kernel(int* blockSums, int nb) {
    if (blockIdx.x == 0 && threadIdx.x == 0) {
        int acc = 0;
        for (int i = 0; i < nb; ++i) { int v = blockSums[i]; blockSums[i] = acc; acc += v; }
    }
}

__global__ void scan_local_kernel(const int* __restrict__ deg, const int* __restrict__ blockSums,
                                  int* __restrict__ rowptr, int n) {
    __shared__ int s[256];
    int i = blockIdx.x * 256 + threadIdx.x;
    int v = (i < n) ? deg[i] : 0;
    s[threadIdx.x] = v;
    __syncthreads();
    for (int off = 1; off < 256; off <<= 1) {
        int t = (threadIdx.x >= off) ? s[threadIdx.x - off] : 0;
        __syncthreads();
        s[threadIdx.x] += t;
        __syncthreads();
    }
    if (i < n) rowptr[i] = blockSums[blockIdx.x] + s[threadIdx.x] - v;  // exclusive
}

__global__ void fill_kernel(const int* __restrict__ src, const int* __restrict__ dst,
                            const int* __restrict__ rowptr, int* __restrict__ cursor,
                            int* __restrict__ nbr, int nEdges) {
    int e = blockIdx.x * blockDim.x + threadIdx.x;
    if (e >= nEdges) return;
    int d = dst[e];
    int pos = atomicAdd(&cursor[d], 1);
    nbr[rowptr[d] + pos] = src[e];
}

// gcnt[g] = #nodes with batch==g via binary search (batch sorted) — round-10 proven
__global__ void gcnt_kernel(const int* __restrict__ batch, float* __restrict__ gcnt,
                            int nNodes, int nGraphs) {
    int g = blockIdx.x * blockDim.x + threadIdx.x;
    if (g >= nGraphs) return;
    int lo = 0, hi = nNodes;
    while (lo < hi) { int m = (lo + hi) >> 1; if (batch[m] < g) lo = m + 1; else hi = m; }
    int lo2 = lo, hi2 = nNodes;
    while (lo2 < hi2) { int m = (lo2 + hi2) >> 1; if (batch[m] <= g) lo2 = m + 1; else hi2 = m; }
    gcnt[g] = (float)(lo2 - lo);
}

// ============ Layer 1: 2 nodes/wave (one per 32-lane half), packed readlane GEMM (r13 proven) ============
__launch_bounds__(512)
__global__ void layer1_fused(const int* __restrict__ nbr, const int* __restrict__ rowptr,
                             const int* __restrict__ deg, const int* __restrict__ node_ids,
                             const float* __restrict__ embed,
                             const float* __restrict__ W1l, const float* __restrict__ b1,
                             const float* __restrict__ W1r, float* __restrict__ h1, int nNodes) {
    __shared__ float sW[EMBED * 2 * HIDDEN];   // 16 KB, (Wl,Wr) interleaved pairs
    int tid = threadIdx.x;
    for (int i = tid; i < EMBED * HIDDEN; i += 512) {
        int k = i >> 6, c = i & 63;
        sW[k * 128 + 2 * c]     = W1l[i];
        sW[k * 128 + 2 * c + 1] = W1r[i];
    }
    __syncthreads();

    int wave = tid >> 6, lane = tid & 63;
    int half = lane >> 5, f = lane & 31;
    float bias = b1[lane];

    for (int p = blockIdx.x * 8 + wave; 2 * p < nNodes; p += gridDim.x * 8) {
        int n0 = 2 * p, n1 = 2 * p + 1;
        bool has1 = (n1 < nNodes);
        int n = half ? n1 : n0;                 // each half owns one node
        bool valid = half ? has1 : true;
        int dg = valid ? deg[n] : 0;
        int st = valid ? rowptr[n] : 0;

        float xv = valid ? embed[(size_t)node_ids[n] * EMBED + f] : 0.f;

        float s0 = 0.f, s1 = 0.f, s2 = 0.f, s3 = 0.f;
        int j = 0;
        for (; j + 3 < dg; j += 4) {
            int i0 = nbr[st + j], i1 = nbr[st + j + 1];
            int i2 = nbr[st + j + 2], i3 = nbr[st + j + 3];
            s0 += embed[(size_t)node_ids[i0] * EMBED + f];
            s1 += embed[(size_t)node_ids[i1] * EMBED + f];
            s2 += embed[(size_t)node_ids[i2] * EMBED + f];
            s3 += embed[(size_t)node_ids[i3] * EMBED + f];
        }
        for (; j < dg; ++j)
            s0 += embed[(size_t)node_ids[nbr[st + j]] * EMBED + f];
        float aggv = ((s0 + s1) + (s2 + s3)) / fmaxf((float)dg, 1.f);   // packed like xv

        float acc0 = bias, acc1 = bias;
        #pragma unroll
        for (int k = 0; k < EMBED; ++k) {
            float2 w = *(const float2*)&sW[k * 128 + 2 * lane];
            acc0 += __shfl(aggv, k) * w.x + __shfl(xv, k) * w.y;
            acc1 += __shfl(aggv, EMBED + k) * w.x + __shfl(xv, EMBED + k) * w.y;
        }
        h1[(size_t)n0 * HIDDEN + lane] = fmaxf(acc0, 0.f);
        if (has1) h1[(size_t)n1 * HIDDEN + lane] = fmaxf(acc1, 0.f);
    }
}

// ============ Layer 2: 4 nodes/wave (16 rows in flight), quad GEMM, bounded run-flush pool ============
__launch_bounds__(512)
__global__ void layer2_fused(const int* __restrict__ nbr, const int* __restrict__ rowptr,
                             const int* __restrict__ deg, const float* __restrict__ h1,
                             const float* __restrict__ W2l, const float* __restrict__ b2,
                             const float* __restrict__ W2r, const int* __restrict__ batch,
                             float* __restrict__ pooled, int nNodes) {
    __shared__ float sW[HIDDEN * 2 * HIDDEN];  // 32 KB, (Wl,Wr) interleaved pairs
    int tid = threadIdx.x;
    for (int i = tid; i < HIDDEN * HIDDEN; i += 512) {
        int k = i >> 6, c = i & 63;
        sW[k * 128 + 2 * c]     = W2l[i];
        sW[k * 128 + 2 * c + 1] = W2r[i];
    }
    __syncthreads();

    int wave = tid >> 6, lane = tid & 63;
    float bias = b2[lane];

    for (int p = blockIdx.x * 8 + wave; 4 * p < nNodes; p += gridDim.x * 8) {
        int n0 = 4 * p;
        int n1 = n0 + 1, n2 = n0 + 2, n3 = n0 + 3;
        bool has1 = (n1 < nNodes), has2 = (n2 < nNodes), has3 = (n3 < nNodes);
        int dg0 = deg[n0],              st0 = rowptr[n0];
        int dg1 = has1 ? deg[n1] : 0,   st1 = has1 ? rowptr[n1] : 0;
        int dg2 = has2 ? deg[n2] : 0,   st2 = has2 ? rowptr[n2] : 0;
        int dg3 = has3 ? deg[n3] : 0,   st3 = has3 ? rowptr[n3] : 0;

        float xv0 = h1[(size_t)n0 * HIDDEN + lane];
        float xv1 = has1 ? h1[(size_t)n1 * HIDDEN + lane] : 0.f;
        float xv2 = has2 ? h1[(size_t)n2 * HIDDEN + lane] : 0.f;
        float xv3 = has3 ? h1[(size_t)n3 * HIDDEN + lane] : 0.f;

        // main interleave up to min degree: 16 independent rows in flight
        float s00 = 0.f, s01 = 0.f, s02 = 0.f, s03 = 0.f;
        float s10 = 0.f, s11 = 0.f, s12 = 0.f, s13 = 0.f;
        float s20 = 0.f, s21 = 0.f, s22 = 0.f, s23 = 0.f;
        float s30 = 0.f, s31 = 0.f, s32 = 0.f, s33 = 0.f;
        int m01 = dg0 < dg1 ? dg0 : dg1;
        int m23 = dg2 < dg3 ? dg2 : dg3;
        int m = m01 < m23 ? m01 : m23;
        int j = 0;
        for (; j + 3 < m; j += 4) {
            int a0 = nbr[st0 + j], a1 = nbr[st0 + j + 1], a2 = nbr[st0 + j + 2], a3 = nbr[st0 + j + 3];
            int b0 = nbr[st1 + j], b1_ = nbr[st1 + j + 1], b2_ = nbr[st1 + j + 2], b3 = nbr[st1 + j + 3];
            int c0 = nbr[st2 + j], c1 = nbr[st2 + j + 1], c2 = nbr[st2 + j + 2], c3 = nbr[st2 + j + 3];
            int d0 = nbr[st3 + j], d1 = nbr[st3 + j + 1], d2 = nbr[st3 + j + 2], d3 = nbr[st3 + j + 3];
            s00 += h1[(size_t)a0 * HIDDEN + lane];
            s01 += h1[(size_t)a1 * HIDDEN + lane];
            s02 += h1[(size_t)a2 * HIDDEN + lane];
            s03 += h1[(size_t)a3 * HIDDEN + lane];
            s10 += h1[(size_t)b0 * HIDDEN + lane];
            s11 += h1[(size_t)b1_ * HIDDEN + lane];
            s12 += h1[(size_t)b2_ * HIDDEN + lane];
            s13 += h1[(size_t)b3 * HIDDEN + lane];
            s20 += h1[(size_t)c0 * HIDDEN + lane];
            s21 += h1[(size_t)c1 * HIDDEN + lane];
            s22 += h1[(size_t)c2 * HIDDEN + lane];
            s23 += h1[(size_t)c3 * HIDDEN + lane];
            s30 += h1[(size_t)d0 * HIDDEN + lane];
            s31 += h1[(size_t)d1 * HIDDEN + lane];
            s32 += h1[(size_t)d2 * HIDDEN + lane];
            s33 += h1[(size_t)d3 * HIDDEN + lane];
        }
        // unified predicated tail: wave-uniform guards, up to 4 rows in flight
        int mx = dg0;
        if (dg1 > mx) mx = dg1;
        if (dg2 > mx) mx = dg2;
        if (dg3 > mx) mx = dg3;
        for (; j < mx; ++j) {
            if (j < dg0) s00 += h1[(size_t)nbr[st0 + j] * HIDDEN + lane];
            if (j < dg1) s10 += h1[(size_t)nbr[st1 + j] * HIDDEN + lane];
            if (j < dg2) s20 += h1[(size_t)nbr[st2 + j] * HIDDEN + lane];
            if (j < dg3) s30 += h1[(size_t)nbr[st3 + j] * HIDDEN + lane];
        }

        float ag0 = ((s00 + s01) + (s02 + s03)) / fmaxf((float)dg0, 1.f);
        float ag1 = ((s10 + s11) + (s12 + s13)) / fmaxf((float)dg1, 1.f);
        float ag2 = ((s20 + s21) + (s22 + s23)) / fmaxf((float)dg2, 1.f);
        float ag3 = ((s30 + s31) + (s32 + s33)) / fmaxf((float)dg3, 1.f);

        // quad GEMM: one ds_read_b64 weight read per k serves all 4 nodes
        float acc0 = bias, acc1 = bias, acc2 = bias, acc3 = bias;
        #pragma unroll 16
        for (int k = 0; k < HIDDEN; ++k) {
            float2 w = *(const float2*)&sW[k * 128 + 2 * lane];
            acc0 += __shfl(ag0, k) * w.x + __shfl(xv0, k) * w.y;
            acc1 += __shfl(ag1, k) * w.x + __shfl(xv1, k) * w.y;
            acc2 += __shfl(ag2, k) * w.x + __shfl(xv2, k) * w.y;
            acc3 += __shfl(ag3, k) * w.x + __shfl(xv3, k) * w.y;
        }
        float a0 = fmaxf(acc0, 0.f);
        float a1 = fmaxf(acc1, 0.f);
        float a2 = fmaxf(acc2, 0.f);
        float a3 = fmaxf(acc3, 0.f);

        // bounded run-flush pooling (batch sorted -> usually one atomic per quad)
        int g0 = batch[n0];
        float s = a0; int gc = g0;
        if (has1) {
            int g1 = batch[n1];
            if (g1 == gc) s += a1;
            else { atomicAdd(&pooled[(size_t)gc * HIDDEN + lane], s); s = a1; gc = g1; }
        }
        if (has2) {
            int g2 = batch[n2];
            if (g2 == gc) s += a2;
            else { atomicAdd(&pooled[(size_t)gc * HIDDEN + lane], s); s = a2; gc = g2; }
        }
        if (has3) {
            int g3 = batch[n3];
            if (g3 == gc) s += a3;
            else { atomicAdd(&pooled[(size_t)gc * HIDDEN + lane], s); s = a3; gc = g3; }
        }
        atomicAdd(&pooled[(size_t)gc * HIDDEN + lane], s);
    }
}

// ============ classifier ============
__global__ void out_kernel(const float* __restrict__ pooled, const float* __restrict__ gcnt,
                           const float* __restrict__ Wout, const float* __restrict__ bout,
                           float* __restrict__ out, int nGraphs) {
    int i = blockIdx.x * blockDim.x + threadIdx.x;
    if (i >= nGraphs * NCLS) return;
    int g = i / NCLS;
    int c = i % NCLS;
    float inv = 1.0f / fmaxf(gcnt[g], 1.0f);
    float acc = bout[c];
    #pragma unroll
    for (int k = 0; k < HIDDEN; ++k)
        acc += pooled[(size_t)g * HIDDEN + k] * inv * Wout[k * NCLS + c];
    out[i] = acc;
}

extern "C" void kernel_launch(void* const* d_in, const int* in_sizes, int n_in,
                              void* d_out, int out_size, void* d_ws, size_t ws_size,
                              hipStream_t stream) {
    const int*   node_ids = (const int*)d_in[0];
    const int*   src      = (const int*)d_in[1];
    const int*   dst      = (const int*)d_in[2];
    const int*   batch    = (const int*)d_in[3];
    const float* embed    = (const float*)d_in[4];
    const float* W1l      = (const float*)d_in[5];
    const float* b1       = (const float*)d_in[6];
    const float* W1r      = (const float*)d_in[7];
    const float* W2l      = (const float*)d_in[8];
    const float* b2       = (const float*)d_in[9];
    const float* W2r      = (const float*)d_in[10];
    const float* Wout     = (const float*)d_in[11];
    const float* bout     = (const float*)d_in[12];

    const int N = in_sizes[0];          // 100000
    const int E = in_sizes[1];          // 1200000
    const int G = out_size / NCLS;      // 1024
    const int NB = (N + 255) / 256;

    // ws: deg[N] | rowptr[N] | cursor[N] | blockSums(pad) | nbr(padE) (ints)
    //     h1[N*64] | pooled[G*64] | gcnt[padG] (floats)
    int* deg       = (int*)d_ws;
    int* rowptr    = deg + N;
    int* cursor    = rowptr + N;
    int* blockSums = cursor + N;
    int* nbr       = blockSums + ((NB + 63) & ~63);
    float* h1      = (float*)(nbr + ((E + 63) & ~63));
    float* pooled  = h1 + (size_t)N * HIDDEN;
    float* gcnt    = pooled + (size_t)G * HIDDEN;

    float* out = (float*)d_out;

    // ---- CSR build ----
    hipMemsetAsync(deg, 0, (size_t)N * sizeof(int), stream);
    hipMemsetAsync(cursor, 0, (size_t)N * sizeof(int), stream);
    deg_kernel<<<(E + 255) / 256, 256, 0, stream>>>(dst, deg, E);
    block_sum_kernel<<<NB, 256, 0, stream>>>(deg, blockSums, N);
    scan_sums_kernel<<<1, 1, 0, stream>>>(blockSums, NB);
    scan_local_kernel<<<NB, 256, 0, stream>>>(deg, blockSums, rowptr, N);
    fill_kernel<<<(E + 255) / 256, 256, 0, stream>>>(src, dst, rowptr, cursor, nbr, E);

    gcnt_kernel<<<(G + 255) / 256, 256, 0, stream>>>(batch, gcnt, N, G);
    hipMemsetAsync(pooled, 0, (size_t)G * HIDDEN * sizeof(float), stream);

    // ---- layer 1 ----
    layer1_fused<<<1024, 512, 0, stream>>>(nbr, rowptr, deg, node_ids, embed,
                                           W1l, b1, W1r, h1, N);

    // ---- layer 2 + pool ----
    layer2_fused<<<1024, 512, 0, stream>>>(nbr, rowptr, deg, h1, W2l, b2, W2r,
                                           batch, pooled, N);

    // ---- classifier ----
    out_kernel<<<(G * NCLS + 255) / 256, 256, 0, stream>>>(pooled, gcnt, Wout, bout, out, G);
}

// Round 18
// 533.517 us; speedup vs baseline: 1.1758x; 1.1758x over previous
//
#include <hip/hip_runtime.h>

#define EMBED 32
#define HIDDEN 64
#define NCLS 10

// ============ CSR construction ============

__global__ void deg_kernel(const int* __restrict__ dst, int* __restrict__ deg, int nEdges) {
    int e = blockIdx.x * blockDim.x + threadIdx.x;
    if (e >= nEdges) return;
    atomicAdd(&deg[dst[e]], 1);
}

__global__ void block_sum_kernel(const int* __restrict__ deg, int* __restrict__ blockSums, int n) {
    __shared__ int s[256];
    int i = blockIdx.x * 256 + threadIdx.x;
    s[threadIdx.x] = (i < n) ? deg[i] : 0;
    __syncthreads();
    for (int off = 128; off > 0; off >>= 1) {
        if (threadIdx.x < off) s[threadIdx.x] += s[threadIdx.x + off];
        __syncthreads();
    }
    if (threadIdx.x == 0) blockSums[blockIdx.x] = s[0];
}

// one-block Kogge-Stone exclusive scan over nb chunk sums (nb <= 512; serial fallback otherwise)
__global__ void scan_sums_kernel(int* blockSums, int nb) {
    __shared__ int s[512];
    int t = threadIdx.x;
    if (nb <= 512) {
        int v = (t < nb) ? blockSums[t] : 0;
        s[t] = v;
        __syncthreads();
        for (int off = 1; off < 512; off <<= 1) {
            int x = (t >= off) ? s[t - off] : 0;
            __syncthreads();
            s[t] += x;
            __syncthreads();
        }
        if (t < nb) blockSums[t] = s[t] - v;   // exclusive
    } else if (t == 0) {
        int acc = 0;
        for (int i = 0; i < nb; ++i) { int v = blockSums[i]; blockSums[i] = acc; acc += v; }
    }
}

__global__ void scan_local_kernel(const int* __restrict__ deg, const int* __restrict__ blockSums,
                                  int* __restrict__ rowptr, int n) {
    __shared__ int s[256];
    int i = blockIdx.x * 256 + threadIdx.x;
    int v = (i < n) ? deg[i] : 0;
    s[threadIdx.x] = v;
    __syncthreads();
    for (int off = 1; off < 256; off <<= 1) {
        int t = (threadIdx.x >= off) ? s[threadIdx.x - off] : 0;
        __syncthreads();
        s[threadIdx.x] += t;
        __syncthreads();
    }
    if (i < n) rowptr[i] = blockSums[blockIdx.x] + s[threadIdx.x] - v;  // exclusive
}

__global__ void fill_kernel(const int* __restrict__ src, const int* __restrict__ dst,
                            const int* __restrict__ rowptr, int* __restrict__ cursor,
                            int* __restrict__ nbr, int nEdges) {
    int e = blockIdx.x * blockDim.x + threadIdx.x;
    if (e >= nEdges) return;
    int d = dst[e];
    int pos = atomicAdd(&cursor[d], 1);
    nbr[rowptr[d] + pos] = src[e];
}

// ============ Layer 1: 2 nodes/wave (one per 32-lane half), packed readlane GEMM (r13 proven) ============
__launch_bounds__(512)
__global__ void layer1_fused(const int* __restrict__ nbr, const int* __restrict__ rowptr,
                             const int* __restrict__ deg, const int* __restrict__ node_ids,
                             const float* __restrict__ embed,
                             const float* __restrict__ W1l, const float* __restrict__ b1,
                             const float* __restrict__ W1r, float* __restrict__ h1, int nNodes) {
    __shared__ float sW[EMBED * 2 * HIDDEN];   // 16 KB, (Wl,Wr) interleaved pairs
    int tid = threadIdx.x;
    for (int i = tid; i < EMBED * HIDDEN; i += 512) {
        int k = i >> 6, c = i & 63;
        sW[k * 128 + 2 * c]     = W1l[i];
        sW[k * 128 + 2 * c + 1] = W1r[i];
    }
    __syncthreads();

    int wave = tid >> 6, lane = tid & 63;
    int half = lane >> 5, f = lane & 31;
    float bias = b1[lane];

    for (int p = blockIdx.x * 8 + wave; 2 * p < nNodes; p += gridDim.x * 8) {
        int n0 = 2 * p, n1 = 2 * p + 1;
        bool has1 = (n1 < nNodes);
        int n = half ? n1 : n0;                 // each half owns one node
        bool valid = half ? has1 : true;
        int dg = valid ? deg[n] : 0;
        int st = valid ? rowptr[n] : 0;

        float xv = valid ? embed[(size_t)node_ids[n] * EMBED + f] : 0.f;

        float s0 = 0.f, s1 = 0.f, s2 = 0.f, s3 = 0.f;
        int j = 0;
        for (; j + 3 < dg; j += 4) {
            int i0 = nbr[st + j], i1 = nbr[st + j + 1];
            int i2 = nbr[st + j + 2], i3 = nbr[st + j + 3];
            s0 += embed[(size_t)node_ids[i0] * EMBED + f];
            s1 += embed[(size_t)node_ids[i1] * EMBED + f];
            s2 += embed[(size_t)node_ids[i2] * EMBED + f];
            s3 += embed[(size_t)node_ids[i3] * EMBED + f];
        }
        for (; j < dg; ++j)
            s0 += embed[(size_t)node_ids[nbr[st + j]] * EMBED + f];
        float aggv = ((s0 + s1) + (s2 + s3)) / fmaxf((float)dg, 1.f);   // packed like xv

        float acc0 = bias, acc1 = bias;
        #pragma unroll
        for (int k = 0; k < EMBED; ++k) {
            float2 w = *(const float2*)&sW[k * 128 + 2 * lane];
            acc0 += __shfl(aggv, k) * w.x + __shfl(xv, k) * w.y;
            acc1 += __shfl(aggv, EMBED + k) * w.x + __shfl(xv, EMBED + k) * w.y;
        }
        h1[(size_t)n0 * HIDDEN + lane] = fmaxf(acc0, 0.f);
        if (has1) h1[(size_t)n1 * HIDDEN + lane] = fmaxf(acc1, 0.f);
    }
}

// ============ Layer 2: 2 nodes/wave interleaved gather (8 rows in flight), dual GEMM, fused pool (r13 proven) ============
__launch_bounds__(512)
__global__ void layer2_fused(const int* __restrict__ nbr, const int* __restrict__ rowptr,
                             const int* __restrict__ deg, const float* __restrict__ h1,
                             const float* __restrict__ W2l, const float* __restrict__ b2,
                             const float* __restrict__ W2r, const int* __restrict__ batch,
                             float* __restrict__ pooled, int nNodes) {
    __shared__ float sW[HIDDEN * 2 * HIDDEN];  // 32 KB, (Wl,Wr) interleaved pairs
    int tid = threadIdx.x;
    for (int i = tid; i < HIDDEN * HIDDEN; i += 512) {
        int k = i >> 6, c = i & 63;
        sW[k * 128 + 2 * c]     = W2l[i];
        sW[k * 128 + 2 * c + 1] = W2r[i];
    }
    __syncthreads();

    int wave = tid >> 6, lane = tid & 63;
    float bias = b2[lane];

    for (int p = blockIdx.x * 8 + wave; 2 * p < nNodes; p += gridDim.x * 8) {
        int n0 = 2 * p, n1 = 2 * p + 1;
        bool has1 = (n1 < nNodes);
        int dg0 = deg[n0], st0 = rowptr[n0];
        int dg1 = has1 ? deg[n1] : 0;
        int st1 = has1 ? rowptr[n1] : 0;

        float xv0 = h1[(size_t)n0 * HIDDEN + lane];
        float xv1 = has1 ? h1[(size_t)n1 * HIDDEN + lane] : 0.f;

        // interleaved gather: both nodes' unroll-4 groups -> 8 independent rows in flight
        float s00 = 0.f, s01 = 0.f, s02 = 0.f, s03 = 0.f;
        float s10 = 0.f, s11 = 0.f, s12 = 0.f, s13 = 0.f;
        int m = dg0 < dg1 ? dg0 : dg1;
        int j = 0;
        for (; j + 3 < m; j += 4) {
            int a0 = nbr[st0 + j], a1 = nbr[st0 + j + 1];
            int a2 = nbr[st0 + j + 2], a3 = nbr[st0 + j + 3];
            int c0 = nbr[st1 + j], c1 = nbr[st1 + j + 1];
            int c2 = nbr[st1 + j + 2], c3 = nbr[st1 + j + 3];
            s00 += h1[(size_t)a0 * HIDDEN + lane];
            s01 += h1[(size_t)a1 * HIDDEN + lane];
            s02 += h1[(size_t)a2 * HIDDEN + lane];
            s03 += h1[(size_t)a3 * HIDDEN + lane];
            s10 += h1[(size_t)c0 * HIDDEN + lane];
            s11 += h1[(size_t)c1 * HIDDEN + lane];
            s12 += h1[(size_t)c2 * HIDDEN + lane];
            s13 += h1[(size_t)c3 * HIDDEN + lane];
        }
        // tails (wave-uniform trip counts, unroll 2)
        int t = j;
        for (; t + 1 < dg0; t += 2) {
            int a0 = nbr[st0 + t], a1 = nbr[st0 + t + 1];
            s00 += h1[(size_t)a0 * HIDDEN + lane];
            s01 += h1[(size_t)a1 * HIDDEN + lane];
        }
        if (t < dg0) s00 += h1[(size_t)nbr[st0 + t] * HIDDEN + lane];
        t = j;
        for (; t + 1 < dg1; t += 2) {
            int c0 = nbr[st1 + t], c1 = nbr[st1 + t + 1];
            s10 += h1[(size_t)c0 * HIDDEN + lane];
            s11 += h1[(size_t)c1 * HIDDEN + lane];
        }
        if (t < dg1) s10 += h1[(size_t)nbr[st1 + t] * HIDDEN + lane];

        float ag0 = ((s00 + s01) + (s02 + s03)) / fmaxf((float)dg0, 1.f);
        float ag1 = ((s10 + s11) + (s12 + s13)) / fmaxf((float)dg1, 1.f);

        // dual GEMM, shared weight reads (one ds_read_b64 per k for both nodes)
        float acc0 = bias, acc1 = bias;
        #pragma unroll 16
        for (int k = 0; k < HIDDEN; ++k) {
            float2 w = *(const float2*)&sW[k * 128 + 2 * lane];
            acc0 += __shfl(ag0, k) * w.x + __shfl(xv0, k) * w.y;
            acc1 += __shfl(ag1, k) * w.x + __shfl(xv1, k) * w.y;
        }
        float a0 = fmaxf(acc0, 0.f);
        int g0 = batch[n0];
        if (has1) {
            float a1 = fmaxf(acc1, 0.f);
            int g1 = batch[n1];
            if (g0 == g1) {
                atomicAdd(&pooled[(size_t)g0 * HIDDEN + lane], a0 + a1);
            } else {
                atomicAdd(&pooled[(size_t)g0 * HIDDEN + lane], a0);
                atomicAdd(&pooled[(size_t)g1 * HIDDEN + lane], a1);
            }
        } else {
            atomicAdd(&pooled[(size_t)g0 * HIDDEN + lane], a0);
        }
    }
}

// ============ classifier (gcnt fused via binary search on sorted batch) ============
__global__ void out_kernel(const float* __restrict__ pooled, const int* __restrict__ batch,
                           const float* __restrict__ Wout, const float* __restrict__ bout,
                           float* __restrict__ out, int nGraphs, int nNodes) {
    int i = blockIdx.x * blockDim.x + threadIdx.x;
    if (i >= nGraphs * NCLS) return;
    int g = i / NCLS;
    int c = i % NCLS;
    int lo = 0, hi = nNodes;
    while (lo < hi) { int m = (lo + hi) >> 1; if (batch[m] < g) lo = m + 1; else hi = m; }
    int lo2 = lo, hi2 = nNodes;
    while (lo2 < hi2) { int m = (lo2 + hi2) >> 1; if (batch[m] <= g) lo2 = m + 1; else hi2 = m; }
    float inv = 1.0f / fmaxf((float)(lo2 - lo), 1.0f);
    float acc = bout[c];
    #pragma unroll
    for (int k = 0; k < HIDDEN; ++k)
        acc += pooled[(size_t)g * HIDDEN + k] * inv * Wout[k * NCLS + c];
    out[i] = acc;
}

extern "C" void kernel_launch(void* const* d_in, const int* in_sizes, int n_in,
                              void* d_out, int out_size, void* d_ws, size_t ws_size,
                              hipStream_t stream) {
    const int*   node_ids = (const int*)d_in[0];
    const int*   src      = (const int*)d_in[1];
    const int*   dst      = (const int*)d_in[2];
    const int*   batch    = (const int*)d_in[3];
    const float* embed    = (const float*)d_in[4];
    const float* W1l      = (const float*)d_in[5];
    const float* b1       = (const float*)d_in[6];
    const float* W1r      = (const float*)d_in[7];
    const float* W2l      = (const float*)d_in[8];
    const float* b2       = (const float*)d_in[9];
    const float* W2r      = (const float*)d_in[10];
    const float* Wout     = (const float*)d_in[11];
    const float* bout     = (const float*)d_in[12];

    const int N = in_sizes[0];          // 100000
    const int E = in_sizes[1];          // 1200000
    const int G = out_size / NCLS;      // 1024
    const int NB = (N + 255) / 256;

    // ws: deg[N] | rowptr[N] | cursor[N] | blockSums(pad) | nbr(padE) (ints)
    //     h1[N*64] | pooled[G*64] (floats)
    int* deg       = (int*)d_ws;
    int* rowptr    = deg + N;
    int* cursor    = rowptr + N;
    int* blockSums = cursor + N;
    int* nbr       = blockSums + ((NB + 63) & ~63);
    float* h1      = (float*)(nbr + ((E + 63) & ~63));
    float* pooled  = h1 + (size_t)N * HIDDEN;

    float* out = (float*)d_out;

    // ---- CSR build ----
    hipMemsetAsync(deg, 0, (size_t)N * sizeof(int), stream);
    hipMemsetAsync(cursor, 0, (size_t)N * sizeof(int), stream);
    deg_kernel<<<(E + 255) / 256, 256, 0, stream>>>(dst, deg, E);
    block_sum_kernel<<<NB, 256, 0, stream>>>(deg, blockSums, N);
    scan_sums_kernel<<<1, 512, 0, stream>>>(blockSums, NB);
    scan_local_kernel<<<NB, 256, 0, stream>>>(deg, blockSums, rowptr, N);
    fill_kernel<<<(E + 255) / 256, 256, 0, stream>>>(src, dst, rowptr, cursor, nbr, E);

    hipMemsetAsync(pooled, 0, (size_t)G * HIDDEN * sizeof(float), stream);

    // ---- layer 1 ----
    layer1_fused<<<1024, 512, 0, stream>>>(nbr, rowptr, deg, node_ids, embed,
                                           W1l, b1, W1r, h1, N);

    // ---- layer 2 + pool ----
    layer2_fused<<<1024, 512, 0, stream>>>(nbr, rowptr, deg, h1, W2l, b2, W2r,
                                           batch, pooled, N);

    // ---- classifier (gcnt fused) ----
    out_kernel<<<(G * NCLS + 255) / 256, 256, 0, stream>>>(pooled, batch, Wout, bout,
                                                           out, G, N);
}